// Round 5
// baseline (134.322 us; speedup 1.0000x reference)
//
#include <hip/hip_runtime.h>

// GMLoss: bidirectional chamfer min + Geman-McClure penalty (MU=1).
// srcs, tgts: [B=8, D=3, N=4096] fp32. Output: scalar fp32.
//
// R5: MFMA formulation. R2-R4 (pure-VALU, 4-5 ops/pair) all plateaued at
// ~41us kernel regardless of memory path -> VALU-issue-bound. Move the
// cross-term GEMM onto the matrix pipe:
//   P[i][j] = |s_i|^2 + |t_j|^2 - 2 s_i.t_j  as  D = A*B + C, K=9 of a
//   16x16x32 bf16 MFMA, with hi/lo bf16 split for fp32-grade accuracy:
//     A row k = [-2ah_x,-2ah_y,-2ah_z, -2ah_x,-2ah_y,-2ah_z, -2al_x,-2al_y,-2al_z]
//     B row k = [ bh_x, bh_y, bh_z,  bl_x, bl_y, bl_z,  bh_x, bh_y, bh_z]
//   Sum = -2(ah.bh + ah.bl + al.bh); dropped |al.bl| ~ 2^-18 -> P err ~2e-5.
//   C-operand = s^2_row + t^2_col (4 v_add per MFMA).
// One MFMA per 16x16 tile gives BOTH directions (row-min = d_src, col-min =
// d_tgt) -> pair count halves vs R2-R4. VALU work: only mins + C-init
// (~35 instr / 512 pairs vs 4/pair before).
// Pipeline: transform (pack bf16 hi/lo + norms) -> chamfer (MFMA + mins;
// col-mins to 16MB partials via plain stores, row-mins -> 1 atomicAdd/blk)
// -> reduce_tgt (stripe-min + GM) -> write_out.
// Fragment layouts per m89/m91-verified mapping:
//   A[m=lane&15][k=quad*8+j], B[n=lane&15][k=quad*8+j],
//   D: col n = lane&15, row m = quad*4+reg.

#define NPTS    4096
#define NB      8
#define NSTRIPE 128   // stripes per batch, 32 src rows each
#define CTPW    64    // col-tiles per wave (4 waves x 64 = 256 tiles)

typedef __attribute__((ext_vector_type(8))) short bf16x8;
typedef __attribute__((ext_vector_type(4))) float floatx4;

// ws layout (bytes)
#define OFF_APACK 0u
#define OFF_BPACK (1u << 20)
#define OFF_SSQ   (2u << 20)
#define OFF_TSQ   ((2u << 20) + (128u << 10))
#define OFF_PART  ((2u << 20) + (256u << 10))
#define OFF_ACC   (OFF_PART + (unsigned)(NB * NSTRIPE * NPTS) * 4u)

union V16 { int4 i; bf16x8 h; };

__device__ __forceinline__ unsigned short f2bf(float f) {
    unsigned u = __float_as_uint(f);
    u += 0x7FFFu + ((u >> 16) & 1u);       // RNE
    return (unsigned short)(u >> 16);
}
__device__ __forceinline__ float bf2f(unsigned short h) {
    return __uint_as_float(((unsigned)h) << 16);
}
__device__ __forceinline__ unsigned pk(unsigned short lo, unsigned short hi) {
    return (unsigned)lo | ((unsigned)hi << 16);
}

// ---------------- Kernel 1: pack hi/lo bf16 + norms ----------------
__global__ __launch_bounds__(256)
void transform_kernel(const float* __restrict__ srcs,
                      const float* __restrict__ tgts,
                      char* __restrict__ ws) {
    const int gid = blockIdx.x * 256 + threadIdx.x;   // b*4096 + j
    const int b = gid >> 12, j = gid & 4095;

    // ---- src -> Apack, Ssq ----
    {
        const float* sp = srcs + b * 3 * NPTS;
        const float x = sp[j], y = sp[NPTS + j], z = sp[2 * NPTS + j];
        const unsigned short hx = f2bf(x), hy = f2bf(y), hz = f2bf(z);
        const unsigned short lx = f2bf(x - bf2f(hx));
        const unsigned short ly = f2bf(y - bf2f(hy));
        const unsigned short lz = f2bf(z - bf2f(hz));
        // -2 * value: exact scaling of a bf16
        const unsigned short a0 = f2bf(-2.0f * bf2f(hx));
        const unsigned short a1 = f2bf(-2.0f * bf2f(hy));
        const unsigned short a2 = f2bf(-2.0f * bf2f(hz));
        const unsigned short l0 = f2bf(-2.0f * bf2f(lx));
        const unsigned short l1 = f2bf(-2.0f * bf2f(ly));
        const unsigned short l2 = f2bf(-2.0f * bf2f(lz));
        int4* Ap = (int4*)(ws + OFF_APACK + (size_t)gid * 32);
        Ap[0] = make_int4((int)pk(a0, a1), (int)pk(a2, a0),
                          (int)pk(a1, a2), (int)pk(l0, l1));
        Ap[1] = make_int4((int)pk(l2, 0), 0, 0, 0);
        ((float*)(ws + OFF_SSQ))[gid] = fmaf(z, z, fmaf(y, y, x * x));
    }
    // ---- tgt -> Bpack, Tsq ----
    {
        const float* tp = tgts + b * 3 * NPTS;
        const float x = tp[j], y = tp[NPTS + j], z = tp[2 * NPTS + j];
        const unsigned short hx = f2bf(x), hy = f2bf(y), hz = f2bf(z);
        const unsigned short lx = f2bf(x - bf2f(hx));
        const unsigned short ly = f2bf(y - bf2f(hy));
        const unsigned short lz = f2bf(z - bf2f(hz));
        int4* Bp = (int4*)(ws + OFF_BPACK + (size_t)gid * 32);
        Bp[0] = make_int4((int)pk(hx, hy), (int)pk(hz, lx),
                          (int)pk(ly, lz), (int)pk(hx, hy));
        Bp[1] = make_int4((int)pk(hz, 0), 0, 0, 0);
        ((float*)(ws + OFF_TSQ))[gid] = fmaf(z, z, fmaf(y, y, x * x));
    }
    if (gid == 0) {
        float* acc = (float*)(ws + OFF_ACC);
        acc[0] = 0.0f;   // d_src GM sum
        acc[1] = 0.0f;   // d_tgt GM sum
    }
}

// ---------------- Kernel 2: MFMA chamfer ----------------
__global__ __launch_bounds__(256, 4)
void chamfer_kernel(char* __restrict__ ws) {
    const int blk    = blockIdx.x;         // 0..1023
    const int b      = blk >> 7;
    const int stripe = blk & 127;          // 32 src rows
    const int wave   = threadIdx.x >> 6;
    const int lane   = threadIdx.x & 63;
    const int col16  = lane & 15;
    const int quad   = lane >> 4;

    const char*  Apack = ws + OFF_APACK;
    const char*  Bpack = ws + OFF_BPACK;
    const float* Ssq   = (const float*)(ws + OFF_SSQ);
    const float* Tsq   = (const float*)(ws + OFF_TSQ);
    float* part = (float*)(ws + OFF_PART) + (size_t)(b * NSTRIPE + stripe) * NPTS;
    float* acc  = (float*)(ws + OFF_ACC);

    // A-frags + s^2 for the stripe's two row-tiles (persist across the loop)
    bf16x8 afrag[2];
    floatx4 s2[2];
#pragma unroll
    for (int rt = 0; rt < 2; rt++) {
        V16 v; v.i = make_int4(0, 0, 0, 0);
        if (quad < 2) {
            const int pt = b * NPTS + stripe * 32 + rt * 16 + col16;
            v.i = *(const int4*)(Apack + (size_t)pt * 32 + quad * 16);
        }
        afrag[rt] = v.h;
        s2[rt] = *(const floatx4*)(Ssq + b * NPTS + stripe * 32 + rt * 16 + quad * 4);
    }

    floatx4 smin0, smin1;
#pragma unroll
    for (int r = 0; r < 4; r++) { smin0[r] = 3.0e38f; smin1[r] = 3.0e38f; }

    const int ct0 = wave * CTPW;
    // prefetch ring (depth 1)
    V16 curB; curB.i = make_int4(0, 0, 0, 0);
    if (quad < 2)
        curB.i = *(const int4*)(Bpack + (size_t)(b * NPTS + ct0 * 16 + col16) * 32 + quad * 16);
    float curT = Tsq[b * NPTS + ct0 * 16 + col16];

    for (int i = 0; i < CTPW; i++) {
        const int ct  = ct0 + i;
        const int ctn = ct0 + ((i + 1 < CTPW) ? i + 1 : i);
        V16 nB; nB.i = make_int4(0, 0, 0, 0);
        if (quad < 2)
            nB.i = *(const int4*)(Bpack + (size_t)(b * NPTS + ctn * 16 + col16) * 32 + quad * 16);
        const float nT = Tsq[b * NPTS + ctn * 16 + col16];

        floatx4 c0, c1;
#pragma unroll
        for (int r = 0; r < 4; r++) { c0[r] = s2[0][r] + curT; c1[r] = s2[1][r] + curT; }
        const floatx4 d0 = __builtin_amdgcn_mfma_f32_16x16x32_bf16(afrag[0], curB.h, c0, 0, 0, 0);
        const floatx4 d1 = __builtin_amdgcn_mfma_f32_16x16x32_bf16(afrag[1], curB.h, c1, 0, 0, 0);

#pragma unroll
        for (int r = 0; r < 4; r++) {
            smin0[r] = fminf(smin0[r], d0[r]);
            smin1[r] = fminf(smin1[r], d1[r]);
        }
        float tg = fminf(fminf(fminf(d0[0], d0[1]), fminf(d0[2], d0[3])),
                         fminf(fminf(d1[0], d1[1]), fminf(d1[2], d1[3])));
        tg = fminf(tg, __shfl_xor(tg, 16, 64));
        tg = fminf(tg, __shfl_xor(tg, 32, 64));
        if (lane < 16) part[ct * 16 + lane] = tg;   // col-min over this stripe

        curB = nB; curT = nT;
    }

    // ---- d_src: reduce over the 16 col-lanes, then cross-wave via LDS ----
#pragma unroll
    for (int off = 1; off < 16; off <<= 1) {
#pragma unroll
        for (int r = 0; r < 4; r++) {
            smin0[r] = fminf(smin0[r], __shfl_xor(smin0[r], off, 64));
            smin1[r] = fminf(smin1[r], __shfl_xor(smin1[r], off, 64));
        }
    }
    __shared__ float sSrc[4][32];
    if (col16 == 0) {
#pragma unroll
        for (int r = 0; r < 4; r++) {
            sSrc[wave][quad * 4 + r]      = smin0[r];   // rows rt0: 0..15
            sSrc[wave][16 + quad * 4 + r] = smin1[r];   // rows rt1: 16..31
        }
    }
    __syncthreads();
    if (threadIdx.x < 32) {
        float m = fminf(fminf(sSrc[0][threadIdx.x], sSrc[1][threadIdx.x]),
                        fminf(sSrc[2][threadIdx.x], sSrc[3][threadIdx.x]));
        m = fmaxf(m, 0.0f);
        float g = m / (m + 1.0f);                      // GM, MU=1
#pragma unroll
        for (int off = 1; off < 32; off <<= 1)
            g += __shfl_xor(g, off, 64);
        if (threadIdx.x == 0) atomicAdd(acc + 0, g);
    }
}

// ---------------- Kernel 3: reduce d_tgt partials ----------------
__global__ __launch_bounds__(256)
void reduce_tgt_kernel(char* __restrict__ ws) {
    const int b   = blockIdx.x >> 4;
    const int col = (blockIdx.x & 15) * 256 + threadIdx.x;
    const float* part = (const float*)(ws + OFF_PART);
    float* acc = (float*)(ws + OFF_ACC);

    float m = 3.0e38f;
    for (int s = 0; s < NSTRIPE; s++)
        m = fminf(m, part[(size_t)(b * NSTRIPE + s) * NPTS + col]);
    m = fmaxf(m, 0.0f);
    float g = m / (m + 1.0f);
#pragma unroll
    for (int off = 1; off < 64; off <<= 1)
        g += __shfl_xor(g, off, 64);
    __shared__ float sp[4];
    if ((threadIdx.x & 63) == 0) sp[threadIdx.x >> 6] = g;
    __syncthreads();
    if (threadIdx.x == 0)
        atomicAdd(acc + 1, sp[0] + sp[1] + sp[2] + sp[3]);
}

// ---------------- Kernel 4: final scalar ----------------
__global__ void write_out_kernel(const char* __restrict__ ws,
                                 float* __restrict__ out) {
    if (threadIdx.x == 0) {
        const float* acc = (const float*)(ws + OFF_ACC);
        out[0] = (acc[0] + acc[1]) * (1.0f / (NB * NPTS));
    }
}

extern "C" void kernel_launch(void* const* d_in, const int* in_sizes, int n_in,
                              void* d_out, int out_size, void* d_ws, size_t ws_size,
                              hipStream_t stream) {
    const float* srcs = (const float*)d_in[0];
    const float* tgts = (const float*)d_in[1];
    float* out = (float*)d_out;
    char* ws = (char*)d_ws;

    transform_kernel<<<dim3(128), dim3(256), 0, stream>>>(srcs, tgts, ws);
    chamfer_kernel<<<dim3(1024), dim3(256), 0, stream>>>(ws);
    reduce_tgt_kernel<<<dim3(128), dim3(256), 0, stream>>>(ws);
    write_out_kernel<<<dim3(1), dim3(64), 0, stream>>>(ws, out);
}

// Round 6
// 95.369 us; speedup vs baseline: 1.4085x; 1.4085x over previous
//
#include <hip/hip_runtime.h>

// GMLoss: bidirectional chamfer min + Geman-McClure penalty (MU=1).
// srcs, tgts: [B=8, D=3, N=4096] fp32. Output: scalar fp32.
//
// R6: 32x32x16 MFMA (1024 pairs/instr), ALL norms inside the K dimension:
//   K slots: [-2sh.th (3) | -2sl.th (3) | -2sh.tl (3) | s2h,s2l x 1 (2) |
//             1 x t2h,t2l (2) | zeros (3)]  -> D = full P tile exactly,
//   no C-operand init, no post-adds. Error: dropped sl.tl + splits ~1e-5.
// Per iter: 1 b128 B-load (64 lanes, no divergence), 1 MFMA, 16 rowmin
// mins, 16-min colmin tree + 1 shfl, 1 coalesced 128B store (~38 VALU /
// 1024 pairs vs R5's ~45/512).
// d_src block sums -> plain stores to bsum[1024] (no same-address atomics);
// reduce kernel folds 16MB col-partials (x8 unrolled loads) + bsum, one
// atomicAdd per block to a single accumulator, ticketed final write.
// Layouts (m74/m101-verified): A[m=lane&31][k=(lane>>5)*8+j], B same with
// n=lane&31; D: col=lane&31, row=(reg&3)+8*(reg>>2)+4*(lane>>5).

#define NPTS    4096
#define NB      8
#define NSTRIPE 128

typedef __attribute__((ext_vector_type(8)))  short bf16x8;
typedef __attribute__((ext_vector_type(16))) float floatx16;

#define OFF_APACK 0u
#define OFF_BPACK (1u << 20)
#define OFF_PART  (2u << 20)
#define OFF_BSUM  (OFF_PART + (unsigned)(NB * NSTRIPE * NPTS) * 4u)
#define OFF_ACC   (OFF_BSUM + 8192u)

union V16 { int4 i; bf16x8 h; };

__device__ __forceinline__ unsigned short f2bf(float f) {
    unsigned u = __float_as_uint(f);
    u += 0x7FFFu + ((u >> 16) & 1u);       // RNE
    return (unsigned short)(u >> 16);
}
__device__ __forceinline__ float bf2f(unsigned short h) {
    return __uint_as_float(((unsigned)h) << 16);
}
__device__ __forceinline__ int pk(unsigned short lo, unsigned short hi) {
    return (int)((unsigned)lo | ((unsigned)hi << 16));
}

// ---------------- Kernel 1: pack K=13 operands + init acc/ticket ----------
__global__ __launch_bounds__(256)
void transform_kernel(const float* __restrict__ srcs,
                      const float* __restrict__ tgts,
                      char* __restrict__ ws) {
    const int gid = blockIdx.x * 256 + threadIdx.x;   // b*4096 + j
    const int b = gid >> 12, j = gid & 4095;
    const unsigned short ONE = 0x3F80;

    {   // ---- src -> Apack ----
        const float* sp = srcs + b * 3 * NPTS;
        const float x = sp[j], y = sp[NPTS + j], z = sp[2 * NPTS + j];
        const unsigned short hx = f2bf(x), hy = f2bf(y), hz = f2bf(z);
        const unsigned short a0 = f2bf(-2.0f * bf2f(hx));
        const unsigned short a1 = f2bf(-2.0f * bf2f(hy));
        const unsigned short a2 = f2bf(-2.0f * bf2f(hz));
        const unsigned short l0 = f2bf(-2.0f * (x - bf2f(hx)));
        const unsigned short l1 = f2bf(-2.0f * (y - bf2f(hy)));
        const unsigned short l2 = f2bf(-2.0f * (z - bf2f(hz)));
        const float s2 = fmaf(z, z, fmaf(y, y, x * x));
        const unsigned short s2h = f2bf(s2);
        const unsigned short s2l = f2bf(s2 - bf2f(s2h));
        int4* Ap = (int4*)(ws + OFF_APACK + (size_t)gid * 32);
        Ap[0] = make_int4(pk(a0, a1), pk(a2, l0), pk(l1, l2), pk(a0, a1));
        Ap[1] = make_int4(pk(a2, s2h), pk(s2l, ONE), pk(ONE, 0), 0);
    }
    {   // ---- tgt -> Bpack ----
        const float* tp = tgts + b * 3 * NPTS;
        const float x = tp[j], y = tp[NPTS + j], z = tp[2 * NPTS + j];
        const unsigned short hx = f2bf(x), hy = f2bf(y), hz = f2bf(z);
        const unsigned short lx = f2bf(x - bf2f(hx));
        const unsigned short ly = f2bf(y - bf2f(hy));
        const unsigned short lz = f2bf(z - bf2f(hz));
        const float t2 = fmaf(z, z, fmaf(y, y, x * x));
        const unsigned short t2h = f2bf(t2);
        const unsigned short t2l = f2bf(t2 - bf2f(t2h));
        int4* Bp = (int4*)(ws + OFF_BPACK + (size_t)gid * 32);
        Bp[0] = make_int4(pk(hx, hy), pk(hz, hx), pk(hy, hz), pk(lx, ly));
        Bp[1] = make_int4(pk(lz, ONE), pk(ONE, t2h), pk(t2l, 0), 0);
    }
    if (gid == 0) {
        float* acc = (float*)(ws + OFF_ACC);
        acc[0] = 0.0f;                       // GM sum accumulator
        ((unsigned*)acc)[1] = 0u;            // ticket
    }
}

// ---------------- Kernel 2: MFMA chamfer ----------------
__global__ __launch_bounds__(256, 4)
void chamfer_kernel(char* __restrict__ ws) {
    const int blk    = blockIdx.x;           // 0..1023
    const int b      = blk >> 7;
    const int stripe = blk & 127;            // 32 src rows
    const int wave   = threadIdx.x >> 6;
    const int lane   = threadIdx.x & 63;
    const int l31    = lane & 31;
    const int half   = lane >> 5;

    const char* Ap = ws + OFF_APACK;
    const char* Bp = ws + OFF_BPACK;
    float* part = (float*)(ws + OFF_PART) + (size_t)(b * NSTRIPE + stripe) * NPTS;

    // A-frag: 32 rows of this stripe, half selects k-half (16B each lane)
    V16 av;
    av.i = *(const int4*)(Ap + (size_t)(b * NPTS + stripe * 32 + l31) * 32 + half * 16);

    floatx16 rowmin, zero;
#pragma unroll
    for (int r = 0; r < 16; r++) { rowmin[r] = 3.0e38f; zero[r] = 0.0f; }

    const int ct0 = wave * 32;               // 32 col-tiles per wave
    const char* bbase = Bp + (size_t)(b * NPTS + ct0 * 32 + l31) * 32 + half * 16;

    V16 cur; cur.i = *(const int4*)bbase;
    for (int i = 0; i < 32; i++) {
        V16 nxt;
        nxt.i = (i < 31) ? *(const int4*)(bbase + (size_t)(i + 1) * 1024) : cur.i;

        const floatx16 d =
            __builtin_amdgcn_mfma_f32_32x32x16_bf16(av.h, cur.h, zero, 0, 0, 0);

        // d_src: accumulate row-mins (16 rows per half-lane-group)
#pragma unroll
        for (int r = 0; r < 16; r++) rowmin[r] = fminf(rowmin[r], d[r]);

        // d_tgt: column min over 32 rows (tree + cross-half shfl)
        float m0 = fminf(fminf(d[0], d[1]),  fminf(d[2], d[3]));
        float m1 = fminf(fminf(d[4], d[5]),  fminf(d[6], d[7]));
        float m2 = fminf(fminf(d[8], d[9]),  fminf(d[10], d[11]));
        float m3 = fminf(fminf(d[12], d[13]), fminf(d[14], d[15]));
        float cmin = fminf(fminf(m0, m1), fminf(m2, m3));
        cmin = fminf(cmin, __shfl_xor(cmin, 32, 64));
        if (lane < 32) part[(ct0 + i) * 32 + lane] = fmaxf(cmin, 0.0f);

        cur = nxt;
    }

    // ---- d_src epilogue: reduce rowmin over the 32 col-lanes ----
#pragma unroll
    for (int off = 1; off < 32; off <<= 1) {
#pragma unroll
        for (int r = 0; r < 16; r++)
            rowmin[r] = fminf(rowmin[r], __shfl_xor(rowmin[r], off, 64));
    }
    __shared__ float sRow[4][32];
    if (l31 == 0) {                          // lanes 0 and 32
#pragma unroll
        for (int r = 0; r < 16; r++)
            sRow[wave][(r & 3) + 8 * (r >> 2) + 4 * half] = rowmin[r];
    }
    __syncthreads();
    if (threadIdx.x < 32) {
        float m = fminf(fminf(sRow[0][threadIdx.x], sRow[1][threadIdx.x]),
                        fminf(sRow[2][threadIdx.x], sRow[3][threadIdx.x]));
        m = fmaxf(m, 0.0f);
        float g = m / (m + 1.0f);            // GM, MU=1
#pragma unroll
        for (int off = 1; off < 32; off <<= 1)
            g += __shfl_xor(g, off, 64);
        if (threadIdx.x == 0)
            ((float*)(ws + OFF_BSUM))[blk] = g;   // plain store, no atomic
    }
}

// ---------------- Kernel 3: fold partials + bsum, ticketed final write ----
__global__ __launch_bounds__(256)
void reduce_kernel(char* __restrict__ ws, float* __restrict__ out) {
    const int b   = blockIdx.x >> 4;
    const int col = (blockIdx.x & 15) * 256 + threadIdx.x;
    const float* part = (const float*)(ws + OFF_PART) + (size_t)b * NSTRIPE * NPTS + col;
    float* acc = (float*)(ws + OFF_ACC);

    float m[8];
#pragma unroll
    for (int u = 0; u < 8; u++) m[u] = 3.0e38f;
    for (int s = 0; s < NSTRIPE; s += 8) {   // 8 independent loads in flight
#pragma unroll
        for (int u = 0; u < 8; u++)
            m[u] = fminf(m[u], part[(size_t)(s + u) * NPTS]);
    }
    float mm = fminf(fminf(fminf(m[0], m[1]), fminf(m[2], m[3])),
                     fminf(fminf(m[4], m[5]), fminf(m[6], m[7])));
    float g = mm / (mm + 1.0f);              // already clamped >= 0 at store
#pragma unroll
    for (int off = 1; off < 64; off <<= 1)
        g += __shfl_xor(g, off, 64);

    __shared__ float sp[4];
    if ((threadIdx.x & 63) == 0) sp[threadIdx.x >> 6] = g;
    __syncthreads();
    if (threadIdx.x == 0) {
        float tot = sp[0] + sp[1] + sp[2] + sp[3];
        const float* bsum = (const float*)(ws + OFF_BSUM);
#pragma unroll
        for (int k = 0; k < 8; k++) tot += bsum[blockIdx.x * 8 + k];
        atomicAdd(acc, tot);
        __threadfence();
        const unsigned old = atomicAdd((unsigned*)acc + 1, 1u);
        if (old == 127u) {                   // last block: exact final write
            const float total = atomicAdd(acc, 0.0f);
            out[0] = total * (1.0f / (NB * NPTS));
        }
    }
}

extern "C" void kernel_launch(void* const* d_in, const int* in_sizes, int n_in,
                              void* d_out, int out_size, void* d_ws, size_t ws_size,
                              hipStream_t stream) {
    const float* srcs = (const float*)d_in[0];
    const float* tgts = (const float*)d_in[1];
    float* out = (float*)d_out;
    char* ws = (char*)d_ws;

    transform_kernel<<<dim3(128), dim3(256), 0, stream>>>(srcs, tgts, ws);
    chamfer_kernel<<<dim3(1024), dim3(256), 0, stream>>>(ws);
    reduce_kernel<<<dim3(128), dim3(256), 0, stream>>>(ws, out);
}